// Round 7
// baseline (505.699 us; speedup 1.0000x reference)
//
#include <hip/hip_runtime.h>
#include <hip/hip_bf16.h>
#include <stdint.h>

// HQQ grouped GEMM, MI355X (gfx950) — round 6 (resubmit; round-6 bench never ran).
//   y[t,o] = x @ (scale*(Wq - zero))  per expert, tokens contiguous.
// Single bf16 x plane (threshold 0.304 tolerates bf16; +~0.02 absmax).
// Scale folded into B at cvt: Bs = bf16_rne(s*w) via v_cvt_pk_bf16_f32;
// MFMA accumulates into acc directly. Zero-term = pseudo K-group 16:
// A cols [r_hi|r_lo|r_hi|0] (rowsum hi/lo), B rows [-zs_hi|-zs_hi|-zs_lo|0].
//
// Round-6 (round 5 spilled: demand ~230 VGPR vs 128 allocated ->
// 0.5 GB scratch traffic, WRITE_SIZE 515 MB):
//  - dropped x_lo plane (halves MFMA + A regs), dropped S (scale-in-B):
//    demand ~160 VGPR -> fits; pipeline unchanged (B depth-2, A depth-1,
//    lgkm-only barrier so VMEM stays in flight across it).
//  - everything else (granule-rotation bank swizzle, XCD swizzle,
//    pseudo-group) carried from the passing round-5 kernel.

namespace {
constexpr int kE = 8;
constexpr int kIn = 1024;
constexpr int kOut = 2816;
constexpr int kGroups = 16;         // quant groups along IN (GS=64)
constexpr int kTok = 2048;
constexpr int kXStride = kIn + 64;  // 1088: x cols + pseudo-group cols
constexpr int kBM = 64;
constexpr int kBN = 128;
constexpr int kBTS = 72;            // Bt LDS row stride in elems (144B)
constexpr int kNT = kOut / kBN;     // 22 n-tiles
constexpr int kGrid = kNT * 256;    // 5632 = 8 * 704
}

typedef __attribute__((ext_vector_type(8))) short short8;
typedef __attribute__((ext_vector_type(4))) float f32x4;
typedef __attribute__((ext_vector_type(4))) int i32x4;
typedef __attribute__((ext_vector_type(4))) unsigned int u32x4;

struct AFrag { short8 h0[2], h1[2]; };  // 16 VGPRs (single plane)

static __device__ __forceinline__ uint32_t fbits(float f) {
  union { float f; uint32_t u; } v; v.f = f; return v.u;
}
static __device__ __forceinline__ unsigned short bf16_rne(float f) {
  uint32_t u = fbits(f);
  u += 0x7fffu + ((u >> 16) & 1u);
  return (unsigned short)(u >> 16);
}
static __device__ __forceinline__ float bf16_f(unsigned short h) {
  union { uint32_t u; float f; } v; v.u = ((uint32_t)h) << 16; return v.f;
}
static __device__ __forceinline__ uint32_t cvt_pk_bf16(float lo, float hi) {
  uint32_t r;
  asm("v_cvt_pk_bf16_f32 %0, %1, %2" : "=v"(r) : "v"(lo), "v"(hi));
  return r;  // low16 = bf16(lo), high16 = bf16(hi), RNE
}
static __device__ __forceinline__ u32x4 pack8(const unsigned short* u) {
  u32x4 r;
#pragma unroll
  for (int ww = 0; ww < 4; ++ww)
    r[ww] = (uint32_t)u[2 * ww] | ((uint32_t)u[2 * ww + 1] << 16);
  return r;
}

// ---------------- prep: x -> bf16 plane + group rowsums (hi/lo) ----------------
__global__ __launch_bounds__(256) void hqq_prep(const float* __restrict__ x,
                                                unsigned short* __restrict__ xhi) {
  const int row = blockIdx.x;
  const int tid = threadIdx.x;
  const f32x4 v = *(const f32x4*)(x + (size_t)row * kIn + tid * 4);
  unsigned long long hp = 0;
  float s = 0.f;
#pragma unroll
  for (int j = 0; j < 4; ++j) {
    float f = v[j];
    hp |= ((unsigned long long)bf16_rne(f)) << (16 * j);
    s += f;
  }
  *(unsigned long long*)(xhi + (size_t)row * kXStride + tid * 4) = hp;
  // group rowsum: 16 consecutive lanes = 64 floats = one group
#pragma unroll
  for (int m = 1; m <= 8; m <<= 1) s += __shfl_xor(s, m, 64);
  if ((tid & 15) == 0) {
    const int g = tid >> 4;
    unsigned short rhi = bf16_rne(s);
    unsigned short rlo = bf16_rne(s - bf16_f(rhi));
    unsigned short* p = xhi + (size_t)row * kXStride + kIn;
    // pseudo A cols: [r_hi | r_lo | r_hi | 0] pairs with B [-zs_hi|-zs_hi|-zs_lo|0]
    p[g] = rhi; p[16 + g] = rlo; p[32 + g] = rhi; p[48 + g] = 0;
  }
}

// ---------------- grouped GEMM ----------------

// A fragment loads for K-group g1 (4x 16B per thread, coalesced 64B rows).
#define ALOAD(g1, AF)                                                   \
  {                                                                     \
    _Pragma("unroll")                                                   \
    for (int mf_ = 0; mf_ < 2; ++mf_) {                                 \
      AF.h0[mf_] = *(const short8*)&xhi[arow[mf_] + (g1) * 64 + klane]; \
      AF.h1[mf_] = *(const short8*)&xhi[arow[mf_] + (g1) * 64 + 32 + klane]; \
    }                                                                   \
  }

// B global load: 8x dwordx4, coalesced (32 lanes x 16B = 512B per k-row).
#define LOADB(g, W)                                                     \
  {                                                                     \
    const int* p_ = wbase + (size_t)(g) * 64 * kOut;                    \
    _Pragma("unroll")                                                   \
    for (int i_ = 0; i_ < 8; ++i_) W[i_] = *(const i32x4*)(p_ + (size_t)i_ * kOut); \
  }

// per-thread o-quad scales for group g (one dwordx4)
#define SCLOAD(g, SC) { SC = *(const f32x4*)(scp + (size_t)(g) * kOut); }

// B cvt(+scale) + transposed LDS write, bank-rotated granule (kc+oq)&7.
#define WRITEB(buf, W, SC)                                              \
  {                                                                     \
    unsigned short* btw_ = &Bt[buf][(oq * 4) * kBTS + (((kc + oq) & 7) * 8)]; \
    _Pragma("unroll")                                                   \
    for (int j_ = 0; j_ < 4; ++j_) {                                    \
      u32x4 o_;                                                         \
      _Pragma("unroll")                                                 \
      for (int ww_ = 0; ww_ < 4; ++ww_) {                               \
        o_[ww_] = cvt_pk_bf16((float)W[2 * ww_][j_] * SC[j_],           \
                              (float)W[2 * ww_ + 1][j_] * SC[j_]);      \
      }                                                                 \
      *(u32x4*)(btw_ + j_ * kBTS) = o_;                                 \
    }                                                                   \
  }

#define ZSLOAD()                                                        \
  {                                                                     \
    _Pragma("unroll")                                                   \
    for (int gg_ = 0; gg_ < 16; ++gg_) {                                \
      zv[gg_] = zrow[(size_t)gg_ * kOut];                               \
      sv[gg_] = srow[(size_t)gg_ * kOut];                               \
    }                                                                   \
  }

// pseudo group 16 into Bt[0]: k0-15=-zs_hi, k16-31=-zs_hi, k32-47=-zs_lo, k48-63=0
// (pairs with A cols [r_hi | r_lo | r_hi | 0]); same granule rotation as WRITEB.
#define PSEUDOWRITE()                                                   \
  {                                                                     \
    unsigned short zh_[16], zl_[16];                                    \
    _Pragma("unroll")                                                   \
    for (int gg_ = 0; gg_ < 16; ++gg_) {                                \
      float zs_ = -(zv[gg_] * sv[gg_]);                                 \
      unsigned short hh_ = bf16_rne(zs_);                               \
      zh_[gg_] = hh_; zl_[gg_] = bf16_rne(zs_ - bf16_f(hh_));           \
    }                                                                   \
    unsigned short* wrow_ = &Bt[0][o_ps * kBTS];                        \
    const int rq_ = (o_ps >> 2) & 7;                                    \
    if (h_ps == 0) {                                                    \
      *(u32x4*)(wrow_ + (((0 + rq_) & 7) * 8)) = pack8(zh_);            \
      *(u32x4*)(wrow_ + (((1 + rq_) & 7) * 8)) = pack8(zh_ + 8);        \
      *(u32x4*)(wrow_ + (((2 + rq_) & 7) * 8)) = pack8(zh_);            \
      *(u32x4*)(wrow_ + (((3 + rq_) & 7) * 8)) = pack8(zh_ + 8);        \
    } else {                                                            \
      u32x4 zz_; zz_[0] = zz_[1] = zz_[2] = zz_[3] = 0;                 \
      *(u32x4*)(wrow_ + (((4 + rq_) & 7) * 8)) = pack8(zl_);            \
      *(u32x4*)(wrow_ + (((5 + rq_) & 7) * 8)) = pack8(zl_ + 8);        \
      *(u32x4*)(wrow_ + (((6 + rq_) & 7) * 8)) = zz_;                   \
      *(u32x4*)(wrow_ + (((7 + rq_) & 7) * 8)) = zz_;                   \
    }                                                                   \
  }

// MFMA phase on Bt[BUF] with resident A-frags AS; acc direct (scale in B).
#define MFMA_PHASE(BUF, AS)                                             \
  {                                                                     \
    const unsigned short* btb_ = &Bt[BUF][0];                           \
    {                                                                   \
      short8 bb[4];                                                     \
      _Pragma("unroll")                                                 \
      for (int nf_ = 0; nf_ < 4; ++nf_)                                 \
        bb[nf_] = *(const short8*)&btb_[broff0[nf_]];                   \
      _Pragma("unroll")                                                 \
      for (int mf_ = 0; mf_ < 2; ++mf_)                                 \
        _Pragma("unroll")                                               \
        for (int nf_ = 0; nf_ < 4; ++nf_)                               \
          acc[mf_][nf_] = __builtin_amdgcn_mfma_f32_16x16x32_bf16(AS.h0[mf_], bb[nf_], acc[mf_][nf_], 0, 0, 0); \
    }                                                                   \
    {                                                                   \
      short8 bb[4];                                                     \
      _Pragma("unroll")                                                 \
      for (int nf_ = 0; nf_ < 4; ++nf_)                                 \
        bb[nf_] = *(const short8*)&btb_[broff1[nf_]];                   \
      _Pragma("unroll")                                                 \
      for (int mf_ = 0; mf_ < 2; ++mf_)                                 \
        _Pragma("unroll")                                               \
        for (int nf_ = 0; nf_ < 4; ++nf_)                               \
          acc[mf_][nf_] = __builtin_amdgcn_mfma_f32_16x16x32_bf16(AS.h1[mf_], bb[nf_], acc[mf_][nf_], 0, 0, 0); \
    }                                                                   \
  }

// One iteration: issue A(g+1), B(g+2)+sc(g+2); MFMA on resident A(g)/Bt[g&1];
// stage B(g+1) (waits its year-old loads only); lgkm-only barrier.
#define BODY(g, AFILL, ASPEND, WFILL, WSPEND, SCFILL, SCSPEND)          \
  {                                                                     \
    ALOAD((g) + 1, AFILL);                                              \
    __builtin_amdgcn_sched_barrier(0);                                  \
    if ((g) <= 13) {                                                    \
      LOADB((g) + 2, WFILL);                                            \
      SCLOAD((g) + 2, SCFILL);                                          \
    } else if ((g) == 14) {                                             \
      ZSLOAD();                                                         \
    }                                                                   \
    __builtin_amdgcn_sched_barrier(0);                                  \
    MFMA_PHASE((g) & 1, ASPEND);                                        \
    if ((g) <= 14) {                                                    \
      WRITEB(((g) + 1) & 1, WSPEND, SCSPEND);                           \
    } else {                                                            \
      PSEUDOWRITE();                                                    \
    }                                                                   \
    asm volatile("s_waitcnt lgkmcnt(0)\n\ts_barrier" ::: "memory");     \
  }

__global__ __launch_bounds__(256, 3) void hqq_gemm(
    const unsigned short* __restrict__ xhi,
    const int* __restrict__ wq, const float* __restrict__ scales,
    const float* __restrict__ zeros, const int* __restrict__ tpe,
    float* __restrict__ out) {
  __shared__ unsigned short Bt[2][kBN * kBTS];  // 2 x 18 KB

  // T1 XCD swizzle (5632 = 8*704): a panel's m-tiles share one XCD L2.
  const int raw = blockIdx.x;
  const int bid = (raw & 7) * (kGrid / 8) + (raw >> 3);

  const int nt = bid >> 8;
  const int em = bid & 255;
  const int e = em >> 5;
  const int mt = em & 31;

  int e_start = 0, cnt = 0, cum = 0;
#pragma unroll
  for (int i = 0; i < kE; ++i) {
    int c = tpe[i];
    if (i == e) { e_start = cum; cnt = c; }
    cum += c;
  }
  if (mt * kBM >= cnt) return;  // block-uniform exit (before any barrier)
  const int e_end = e_start + cnt;
  const int row0 = e_start + mt * kBM;
  const int nn = nt * kBN;

  const int tid = threadIdx.x;
  const int lane = tid & 63;
  const int wid = tid >> 6;
  const int wm = wid >> 1;
  const int wn = wid & 1;

  // A fragment row bases (clamped)
  size_t arow[2];
#pragma unroll
  for (int mf = 0; mf < 2; ++mf) {
    int r = row0 + wm * 32 + mf * 16 + (lane & 15);
    if (r > kTok - 1) r = kTok - 1;
    arow[mf] = (size_t)r * kXStride;
  }
  const int klane = (lane >> 4) * 8;  // A k-offset within a 32-col half

  // B read offsets, granule-rotated: k-chunk c of row nrow lives at granule
  // (c + (nrow>>2)) & 7.  ks=0 -> c = gk (0..3); ks=1 -> c = gk+4.
  int broff0[4], broff1[4];
#pragma unroll
  for (int nf = 0; nf < 4; ++nf) {
    const int nrow = wn * 64 + nf * 16 + (lane & 15);
    const int gk = lane >> 4;  // 0..3
    broff0[nf] = nrow * kBTS + (((gk + (nrow >> 2)) & 7) * 8);
    broff1[nf] = nrow * kBTS + (((gk + 4 + (nrow >> 2)) & 7) * 8);
  }

  // B staging thread mapping: 8k x 4o per thread
  const int oq = tid & 31;
  const int kc = tid >> 5;
  const int* wbase = wq + (size_t)e * kIn * kOut + (size_t)(kc * 8) * kOut + nn + oq * 4;
  const float* scp = scales + (size_t)e * kGroups * kOut + nn + oq * 4;

  // pseudo-group staging mapping
  const int o_ps = tid >> 1;
  const int h_ps = tid & 1;
  const float* zrow = zeros + (size_t)e * kGroups * kOut + nn + o_ps;
  const float* srow = scales + (size_t)e * kGroups * kOut + nn + o_ps;

  i32x4 wA[8], wB[8];
  AFrag aA, aB;
  f32x4 scA, scB;
  float zv[16], sv[16];
  f32x4 acc[2][4];
#pragma unroll
  for (int a = 0; a < 2; ++a)
#pragma unroll
    for (int b = 0; b < 4; ++b) acc[a][b] = 0.f;

  // ---- prologue: Bt[0]=B(0); wB=B(1), aA=A(0) in flight ----
  LOADB(0, wA);
  SCLOAD(0, scA);
  LOADB(1, wB);
  SCLOAD(1, scB);
  ALOAD(0, aA);
  WRITEB(0, wA, scA);  // waits wA/scA only (younger loads stay in flight)
  asm volatile("s_waitcnt lgkmcnt(0)\n\ts_barrier" ::: "memory");

  // ---- main loop: 16 real groups; even: spend aA/wB, fill aB/wA ----
  for (int gg = 0; gg < 16; gg += 2) {
    BODY(gg,     aB, aA, wA, wB, scA, scB);
    BODY(gg + 1, aA, aB, wB, wA, scB, scA);
  }

  // ---- iter 16: pseudo group (A(16) resident in aA, Bt[0] staged) ----
  MFMA_PHASE(0, aA);

  // ---- epilogue: predicated fp32 stores ----
  float* ob = out + nn + wn * 64 + (lane & 15);
#pragma unroll
  for (int mf = 0; mf < 2; ++mf)
#pragma unroll
    for (int i = 0; i < 4; ++i) {
      const int t = row0 + wm * 32 + mf * 16 + (lane >> 4) * 4 + i;
      if (t < e_end) {
#pragma unroll
        for (int nf = 0; nf < 4; ++nf)
          ob[(size_t)t * kOut + nf * 16] = acc[mf][nf][i];
      }
    }
}

extern "C" void kernel_launch(void* const* d_in, const int* in_sizes, int n_in,
                              void* d_out, int out_size, void* d_ws, size_t ws_size,
                              hipStream_t stream) {
  const float* x = (const float*)d_in[0];
  const int* tpe = (const int*)d_in[1];
  const int* wq = (const int*)d_in[2];
  const float* scales = (const float*)d_in[3];
  const float* zeros = (const float*)d_in[4];
  float* out = (float*)d_out;

  // ws: xhi [2048*1088] bf16 (~4.5 MB)
  unsigned short* xhi = (unsigned short*)d_ws;

  hqq_prep<<<dim3(kTok), dim3(256), 0, stream>>>(x, xhi);
  hqq_gemm<<<dim3(kGrid), dim3(256), 0, stream>>>(xhi, wq, scales, zeros, tpe, out);
}

// Round 8
// 216.073 us; speedup vs baseline: 2.3404x; 2.3404x over previous
//
#include <hip/hip_runtime.h>
#include <hip/hip_bf16.h>
#include <stdint.h>

// HQQ grouped GEMM, MI355X (gfx950) — round 8.
// Architecture change: rounds 2-7 showed the in-loop int32->bf16 conversion
// forces a ~100-VGPR reg-staging pipeline that this allocator spills to
// scratch (r5: 0.5 GB, r7: 0.6 GB scratch traffic; VGPR pinned at 256/N).
// Fix: dequantize ONCE in a prep pass -> Wt[e][o][k] bf16 = s*(w-z),
// TRANSPOSED and with the frag-read XOR swizzle (slot h = g ^ (o&7) per
// 64-k chunk) baked into the global layout. The GEMM becomes a plain
// grouped bf16 GEMM, m97-structure: B via global_load_lds (no VGPR, no
// VALU cvt), A direct-from-global (L2/L3-resident), 2-phase pipeline with
// one vmcnt(0)+barrier per K-tile. Reg demand ~90 -> no spill possible.
// Host branches on ws_size (needs 50.6 MB); fallback = round-6 kernel
// (passed, 400us) if ws is too small.

namespace {
constexpr int kE = 8;
constexpr int kIn = 1024;
constexpr int kOut = 2816;
constexpr int kGroups = 16;         // quant groups along IN (GS=64)
constexpr int kTok = 2048;
constexpr int kXStride = kIn + 64;  // 1088: x cols + pseudo cols (fallback uses them)
constexpr int kBM = 64;
constexpr int kBN = 128;
constexpr int kBTS = 72;            // fallback Bt LDS row stride
constexpr int kNT = kOut / kBN;     // 22 n-tiles
constexpr int kGrid = kNT * 256;    // 5632 = 8 * 704
}

typedef __attribute__((ext_vector_type(8))) short short8;
typedef __attribute__((ext_vector_type(4))) float f32x4;
typedef __attribute__((ext_vector_type(4))) int i32x4;
typedef __attribute__((ext_vector_type(4))) unsigned int u32x4;

struct AFrag { short8 h0[2], h1[2]; };  // 16 VGPRs

static __device__ __forceinline__ uint32_t fbits(float f) {
  union { float f; uint32_t u; } v; v.f = f; return v.u;
}
static __device__ __forceinline__ unsigned short bf16_rne(float f) {
  uint32_t u = fbits(f);
  u += 0x7fffu + ((u >> 16) & 1u);
  return (unsigned short)(u >> 16);
}
static __device__ __forceinline__ float bf16_f(unsigned short h) {
  union { uint32_t u; float f; } v; v.u = ((uint32_t)h) << 16; return v.f;
}
static __device__ __forceinline__ uint32_t cvt_pk_bf16(float lo, float hi) {
  uint32_t r;
  asm("v_cvt_pk_bf16_f32 %0, %1, %2" : "=v"(r) : "v"(lo), "v"(hi));
  return r;
}
static __device__ __forceinline__ u32x4 pack8(const unsigned short* u) {
  u32x4 r;
#pragma unroll
  for (int ww = 0; ww < 4; ++ww)
    r[ww] = (uint32_t)u[2 * ww] | ((uint32_t)u[2 * ww + 1] << 16);
  return r;
}

// ---------------- prep: x -> bf16 plane + group rowsums (shared by both paths)
__global__ __launch_bounds__(256) void hqq_prep(const float* __restrict__ x,
                                                unsigned short* __restrict__ xhi) {
  const int row = blockIdx.x;
  const int tid = threadIdx.x;
  const f32x4 v = *(const f32x4*)(x + (size_t)row * kIn + tid * 4);
  unsigned long long hp = 0;
  float s = 0.f;
#pragma unroll
  for (int j = 0; j < 4; ++j) {
    float f = v[j];
    hp |= ((unsigned long long)bf16_rne(f)) << (16 * j);
    s += f;
  }
  *(unsigned long long*)(xhi + (size_t)row * kXStride + tid * 4) = hp;
#pragma unroll
  for (int m = 1; m <= 8; m <<= 1) s += __shfl_xor(s, m, 64);
  if ((tid & 15) == 0) {
    const int g = tid >> 4;
    unsigned short rhi = bf16_rne(s);
    unsigned short rlo = bf16_rne(s - bf16_f(rhi));
    unsigned short* p = xhi + (size_t)row * kXStride + kIn;
    p[g] = rhi; p[16 + g] = rlo; p[32 + g] = rhi; p[48 + g] = 0;
  }
}

// ---------------- primary path: dequant prep -------------------------------
// Wt[e][o][k'] bf16 = s*(w-z), transposed, swizzled: within each 64-k chunk,
// content granule g (8 bf16) is stored at slot h = g ^ (o&7).
__global__ __launch_bounds__(256) void hqq_dequant(
    const int* __restrict__ wq, const float* __restrict__ scales,
    const float* __restrict__ zeros, unsigned short* __restrict__ wt) {
  __shared__ unsigned short T[64][72];  // [o][k] tile, padded to 144B rows
  const int bidx = blockIdx.x;          // 8 e * 16 kt * 44 ot = 5632
  const int e = bidx / 704;
  const int rem = bidx % 704;
  const int kt = rem / 44;              // == quant group
  const int ot = rem % 44;
  const int o0 = ot * 64, k0 = kt * 64;
  const int tid = threadIdx.x;
  const int oq = tid & 15;   // o-quad (4 o's)
  const int r = tid >> 4;    // k rows 4r..4r+3

  const float* sp = scales + ((size_t)e * kGroups + kt) * kOut + o0 + oq * 4;
  const float* zp = zeros + ((size_t)e * kGroups + kt) * kOut + o0 + oq * 4;
  const f32x4 s4 = *(const f32x4*)sp;
  const f32x4 z4 = *(const f32x4*)zp;
  const int* wp = wq + ((size_t)e * kIn + k0 + r * 4) * kOut + o0 + oq * 4;
  i32x4 w4[4];
#pragma unroll
  for (int rr = 0; rr < 4; ++rr) w4[rr] = *(const i32x4*)(wp + (size_t)rr * kOut);

#pragma unroll
  for (int j = 0; j < 4; ++j) {  // transpose: 4 k values for o = oq*4+j
    float v0 = s4[j] * ((float)w4[0][j] - z4[j]);
    float v1 = s4[j] * ((float)w4[1][j] - z4[j]);
    float v2 = s4[j] * ((float)w4[2][j] - z4[j]);
    float v3 = s4[j] * ((float)w4[3][j] - z4[j]);
    unsigned int* dst = (unsigned int*)&T[oq * 4 + j][r * 4];
    dst[0] = cvt_pk_bf16(v0, v1);
    dst[1] = cvt_pk_bf16(v2, v3);
  }
  __syncthreads();
  // write out 512 granules; slot h holds content granule g = h ^ (o&7)
#pragma unroll
  for (int gi = 0; gi < 2; ++gi) {
    const int G = tid + gi * 256;
    const int o = G >> 3, h = G & 7;
    const int g = h ^ (o & 7);
    const u32x4 val = *(const u32x4*)&T[o][g * 8];
    unsigned short* dst = wt + ((size_t)e * kOut + o0 + o) * kIn + k0 + h * 8;
    *(u32x4*)dst = val;
  }
}

// ---------------- primary GEMM: plain grouped bf16, m97-structure ----------
__global__ __launch_bounds__(256) void hqq_gemm2(
    const unsigned short* __restrict__ xhi, const unsigned short* __restrict__ wt,
    const int* __restrict__ tpe, float* __restrict__ out) {
  __shared__ unsigned short Bt[2][kBN * 64];  // 2 x 16 KB, [o][swz-k] linear

  const int raw = blockIdx.x;
  const int bid = (raw & 7) * (kGrid / 8) + (raw >> 3);  // XCD swizzle
  const int nt = bid >> 8;
  const int em = bid & 255;
  const int e = em >> 5;
  const int mt = em & 31;

  int e_start = 0, cnt = 0, cum = 0;
#pragma unroll
  for (int i = 0; i < kE; ++i) {
    int c = tpe[i];
    if (i == e) { e_start = cum; cnt = c; }
    cum += c;
  }
  if (mt * kBM >= cnt) return;
  const int e_end = e_start + cnt;
  const int row0 = e_start + mt * kBM;
  const int nn = nt * kBN;

  const int tid = threadIdx.x;
  const int lane = tid & 63;
  const int wid = tid >> 6;
  const int wm = wid >> 1;
  const int wn = wid & 1;

  size_t arow[2];
#pragma unroll
  for (int mf = 0; mf < 2; ++mf) {
    int r = row0 + wm * 32 + mf * 16 + (lane & 15);
    if (r > kTok - 1) r = kTok - 1;
    arow[mf] = (size_t)r * kXStride;
  }
  const int klane = (lane >> 4) * 8;

  // B-frag LDS offsets: row nrow, k-granule gk stored at slot gk^(nrow&7)
  int broff0[4], broff1[4];
#pragma unroll
  for (int nf = 0; nf < 4; ++nf) {
    const int nrow = wn * 64 + nf * 16 + (lane & 15);
    const int gk = lane >> 4;  // 0..3
    broff0[nf] = nrow * 64 + ((gk ^ (nrow & 7)) * 8);
    broff1[nf] = nrow * 64 + (((gk + 4) ^ (nrow & 7)) * 8);
  }

  // staging: wave wid covers o-rows [wid*32, wid*32+32); instr i: 8 rows.
  // global is pre-swizzled -> lane l reads slot (l&7) of row (l>>3): LINEAR.
  const unsigned short* gW =
      wt + ((size_t)e * kOut + nn + wid * 32 + (lane >> 3)) * kIn + (lane & 7) * 8;
  const int ldsbase = wid * 32 * 64;  // elements

#define STAGE2(t, buf)                                                        \
  {                                                                           \
    _Pragma("unroll")                                                         \
    for (int i_ = 0; i_ < 4; ++i_) {                                          \
      __builtin_amdgcn_global_load_lds(                                       \
          (const __attribute__((address_space(1))) unsigned int*)(gW + (size_t)(t) * 64 + i_ * 8 * kIn), \
          (__attribute__((address_space(3))) unsigned int*)(&Bt[buf][ldsbase + i_ * 8 * 64]), \
          16, 0, 0);                                                          \
    }                                                                         \
  }

  f32x4 acc[2][4];
#pragma unroll
  for (int a = 0; a < 2; ++a)
#pragma unroll
    for (int b = 0; b < 4; ++b) acc[a][b] = 0.f;

  // prologue
  STAGE2(0, 0);
  asm volatile("s_waitcnt vmcnt(0)\n\ts_barrier" ::: "memory");

  for (int t = 0; t < 16; ++t) {
    // A loads for this tile (oldest in VMEM queue)
    short8 ah0[2], ah1[2];
#pragma unroll
    for (int mf = 0; mf < 2; ++mf) {
      ah0[mf] = *(const short8*)&xhi[arow[mf] + t * 64 + klane];
      ah1[mf] = *(const short8*)&xhi[arow[mf] + t * 64 + 32 + klane];
    }
    __builtin_amdgcn_sched_barrier(0);
    if (t < 15) STAGE2(t + 1, (t + 1) & 1);  // youngest: flies through MFMA
    __builtin_amdgcn_sched_barrier(0);

    const unsigned short* btb = &Bt[t & 1][0];
    {
      short8 bb[4];
#pragma unroll
      for (int nf = 0; nf < 4; ++nf) bb[nf] = *(const short8*)&btb[broff0[nf]];
#pragma unroll
      for (int mf = 0; mf < 2; ++mf)
#pragma unroll
        for (int nf = 0; nf < 4; ++nf)
          acc[mf][nf] = __builtin_amdgcn_mfma_f32_16x16x32_bf16(ah0[mf], bb[nf], acc[mf][nf], 0, 0, 0);
    }
    {
      short8 bb[4];
#pragma unroll
      for (int nf = 0; nf < 4; ++nf) bb[nf] = *(const short8*)&btb[broff1[nf]];
#pragma unroll
      for (int mf = 0; mf < 2; ++mf)
#pragma unroll
        for (int nf = 0; nf < 4; ++nf)
          acc[mf][nf] = __builtin_amdgcn_mfma_f32_16x16x32_bf16(ah1[mf], bb[nf], acc[mf][nf], 0, 0, 0);
    }
    asm volatile("s_waitcnt vmcnt(0)\n\ts_barrier" ::: "memory");
  }
#undef STAGE2

  float* ob = out + nn + wn * 64 + (lane & 15);
#pragma unroll
  for (int mf = 0; mf < 2; ++mf)
#pragma unroll
    for (int i = 0; i < 4; ++i) {
      const int t = row0 + wm * 32 + mf * 16 + (lane >> 4) * 4 + i;
      if (t < e_end) {
#pragma unroll
        for (int nf = 0; nf < 4; ++nf)
          ob[(size_t)t * kOut + nf * 16] = acc[mf][nf][i];
      }
    }
}

// ======================= fallback path (round-6, passing) ===================
#define ALOAD(g1, AF)                                                   \
  {                                                                     \
    _Pragma("unroll")                                                   \
    for (int mf_ = 0; mf_ < 2; ++mf_) {                                 \
      AF.h0[mf_] = *(const short8*)&xhi[arow[mf_] + (g1) * 64 + klane]; \
      AF.h1[mf_] = *(const short8*)&xhi[arow[mf_] + (g1) * 64 + 32 + klane]; \
    }                                                                   \
  }
#define LOADB(g, W)                                                     \
  {                                                                     \
    const int* p_ = wbase + (size_t)(g) * 64 * kOut;                    \
    _Pragma("unroll")                                                   \
    for (int i_ = 0; i_ < 8; ++i_) W[i_] = *(const i32x4*)(p_ + (size_t)i_ * kOut); \
  }
#define SCLOAD(g, SC) { SC = *(const f32x4*)(scp + (size_t)(g) * kOut); }
#define WRITEB(buf, W, SC)                                              \
  {                                                                     \
    unsigned short* btw_ = &Bt[buf][(oq * 4) * kBTS + (((kc + oq) & 7) * 8)]; \
    _Pragma("unroll")                                                   \
    for (int j_ = 0; j_ < 4; ++j_) {                                    \
      u32x4 o_;                                                         \
      _Pragma("unroll")                                                 \
      for (int ww_ = 0; ww_ < 4; ++ww_) {                               \
        o_[ww_] = cvt_pk_bf16((float)W[2 * ww_][j_] * SC[j_],           \
                              (float)W[2 * ww_ + 1][j_] * SC[j_]);      \
      }                                                                 \
      *(u32x4*)(btw_ + j_ * kBTS) = o_;                                 \
    }                                                                   \
  }
#define ZSLOAD()                                                        \
  {                                                                     \
    _Pragma("unroll")                                                   \
    for (int gg_ = 0; gg_ < 16; ++gg_) {                                \
      zv[gg_] = zrow[(size_t)gg_ * kOut];                               \
      sv[gg_] = srow[(size_t)gg_ * kOut];                               \
    }                                                                   \
  }
#define PSEUDOWRITE()                                                   \
  {                                                                     \
    unsigned short zh_[16], zl_[16];                                    \
    _Pragma("unroll")                                                   \
    for (int gg_ = 0; gg_ < 16; ++gg_) {                                \
      float zs_ = -(zv[gg_] * sv[gg_]);                                 \
      unsigned short hh_ = bf16_rne(zs_);                               \
      zh_[gg_] = hh_; zl_[gg_] = bf16_rne(zs_ - bf16_f(hh_));           \
    }                                                                   \
    unsigned short* wrow_ = &Bt[0][o_ps * kBTS];                        \
    const int rq_ = (o_ps >> 2) & 7;                                    \
    if (h_ps == 0) {                                                    \
      *(u32x4*)(wrow_ + (((0 + rq_) & 7) * 8)) = pack8(zh_);            \
      *(u32x4*)(wrow_ + (((1 + rq_) & 7) * 8)) = pack8(zh_ + 8);        \
      *(u32x4*)(wrow_ + (((2 + rq_) & 7) * 8)) = pack8(zh_);            \
      *(u32x4*)(wrow_ + (((3 + rq_) & 7) * 8)) = pack8(zh_ + 8);        \
    } else {                                                            \
      u32x4 zz_; zz_[0] = zz_[1] = zz_[2] = zz_[3] = 0;                 \
      *(u32x4*)(wrow_ + (((4 + rq_) & 7) * 8)) = pack8(zl_);            \
      *(u32x4*)(wrow_ + (((5 + rq_) & 7) * 8)) = pack8(zl_ + 8);        \
      *(u32x4*)(wrow_ + (((6 + rq_) & 7) * 8)) = zz_;                   \
      *(u32x4*)(wrow_ + (((7 + rq_) & 7) * 8)) = zz_;                   \
    }                                                                   \
  }
#define MFMA_PHASE(BUF, AS)                                             \
  {                                                                     \
    const unsigned short* btb_ = &Bt[BUF][0];                           \
    {                                                                   \
      short8 bb[4];                                                     \
      _Pragma("unroll")                                                 \
      for (int nf_ = 0; nf_ < 4; ++nf_)                                 \
        bb[nf_] = *(const short8*)&btb_[broff0[nf_]];                   \
      _Pragma("unroll")                                                 \
      for (int mf_ = 0; mf_ < 2; ++mf_)                                 \
        _Pragma("unroll")                                               \
        for (int nf_ = 0; nf_ < 4; ++nf_)                               \
          acc[mf_][nf_] = __builtin_amdgcn_mfma_f32_16x16x32_bf16(AS.h0[mf_], bb[nf_], acc[mf_][nf_], 0, 0, 0); \
    }                                                                   \
    {                                                                   \
      short8 bb[4];                                                     \
      _Pragma("unroll")                                                 \
      for (int nf_ = 0; nf_ < 4; ++nf_)                                 \
        bb[nf_] = *(const short8*)&btb_[broff1[nf_]];                   \
      _Pragma("unroll")                                                 \
      for (int mf_ = 0; mf_ < 2; ++mf_)                                 \
        _Pragma("unroll")                                               \
        for (int nf_ = 0; nf_ < 4; ++nf_)                               \
          acc[mf_][nf_] = __builtin_amdgcn_mfma_f32_16x16x32_bf16(AS.h1[mf_], bb[nf_], acc[mf_][nf_], 0, 0, 0); \
    }                                                                   \
  }
#define BODY(g, AFILL, ASPEND, WFILL, WSPEND, SCFILL, SCSPEND)          \
  {                                                                     \
    ALOAD((g) + 1, AFILL);                                              \
    __builtin_amdgcn_sched_barrier(0);                                  \
    if ((g) <= 13) {                                                    \
      LOADB((g) + 2, WFILL);                                            \
      SCLOAD((g) + 2, SCFILL);                                          \
    } else if ((g) == 14) {                                             \
      ZSLOAD();                                                         \
    }                                                                   \
    __builtin_amdgcn_sched_barrier(0);                                  \
    MFMA_PHASE((g) & 1, ASPEND);                                        \
    if ((g) <= 14) {                                                    \
      WRITEB(((g) + 1) & 1, WSPEND, SCSPEND);                           \
    } else {                                                            \
      PSEUDOWRITE();                                                    \
    }                                                                   \
    asm volatile("s_waitcnt lgkmcnt(0)\n\ts_barrier" ::: "memory");     \
  }

__global__ __launch_bounds__(256, 3) void hqq_gemm(
    const unsigned short* __restrict__ xhi,
    const int* __restrict__ wq, const float* __restrict__ scales,
    const float* __restrict__ zeros, const int* __restrict__ tpe,
    float* __restrict__ out) {
  __shared__ unsigned short Bt[2][kBN * kBTS];

  const int raw = blockIdx.x;
  const int bid = (raw & 7) * (kGrid / 8) + (raw >> 3);
  const int nt = bid >> 8;
  const int em = bid & 255;
  const int e = em >> 5;
  const int mt = em & 31;

  int e_start = 0, cnt = 0, cum = 0;
#pragma unroll
  for (int i = 0; i < kE; ++i) {
    int c = tpe[i];
    if (i == e) { e_start = cum; cnt = c; }
    cum += c;
  }
  if (mt * kBM >= cnt) return;
  const int e_end = e_start + cnt;
  const int row0 = e_start + mt * kBM;
  const int nn = nt * kBN;

  const int tid = threadIdx.x;
  const int lane = tid & 63;
  const int wid = tid >> 6;
  const int wm = wid >> 1;
  const int wn = wid & 1;

  size_t arow[2];
#pragma unroll
  for (int mf = 0; mf < 2; ++mf) {
    int r = row0 + wm * 32 + mf * 16 + (lane & 15);
    if (r > kTok - 1) r = kTok - 1;
    arow[mf] = (size_t)r * kXStride;
  }
  const int klane = (lane >> 4) * 8;

  int broff0[4], broff1[4];
#pragma unroll
  for (int nf = 0; nf < 4; ++nf) {
    const int nrow = wn * 64 + nf * 16 + (lane & 15);
    const int gk = lane >> 4;
    broff0[nf] = nrow * kBTS + (((gk + (nrow >> 2)) & 7) * 8);
    broff1[nf] = nrow * kBTS + (((gk + 4 + (nrow >> 2)) & 7) * 8);
  }

  const int oq = tid & 31;
  const int kc = tid >> 5;
  const int* wbase = wq + (size_t)e * kIn * kOut + (size_t)(kc * 8) * kOut + nn + oq * 4;
  const float* scp = scales + (size_t)e * kGroups * kOut + nn + oq * 4;

  const int o_ps = tid >> 1;
  const int h_ps = tid & 1;
  const float* zrow = zeros + (size_t)e * kGroups * kOut + nn + o_ps;
  const float* srow = scales + (size_t)e * kGroups * kOut + nn + o_ps;

  i32x4 wA[8], wB[8];
  AFrag aA, aB;
  f32x4 scA, scB;
  float zv[16], sv[16];
  f32x4 acc[2][4];
#pragma unroll
  for (int a = 0; a < 2; ++a)
#pragma unroll
    for (int b = 0; b < 4; ++b) acc[a][b] = 0.f;

  LOADB(0, wA);
  SCLOAD(0, scA);
  LOADB(1, wB);
  SCLOAD(1, scB);
  ALOAD(0, aA);
  WRITEB(0, wA, scA);
  asm volatile("s_waitcnt lgkmcnt(0)\n\ts_barrier" ::: "memory");

  for (int gg = 0; gg < 16; gg += 2) {
    BODY(gg,     aB, aA, wA, wB, scA, scB);
    BODY(gg + 1, aA, aB, wB, wA, scB, scA);
  }
  MFMA_PHASE(0, aA);

  float* ob = out + nn + wn * 64 + (lane & 15);
#pragma unroll
  for (int mf = 0; mf < 2; ++mf)
#pragma unroll
    for (int i = 0; i < 4; ++i) {
      const int t = row0 + wm * 32 + mf * 16 + (lane >> 4) * 4 + i;
      if (t < e_end) {
#pragma unroll
        for (int nf = 0; nf < 4; ++nf)
          ob[(size_t)t * kOut + nf * 16] = acc[mf][nf][i];
      }
    }
}

extern "C" void kernel_launch(void* const* d_in, const int* in_sizes, int n_in,
                              void* d_out, int out_size, void* d_ws, size_t ws_size,
                              hipStream_t stream) {
  const float* x = (const float*)d_in[0];
  const int* tpe = (const int*)d_in[1];
  const int* wq = (const int*)d_in[2];
  const float* scales = (const float*)d_in[3];
  const float* zeros = (const float*)d_in[4];
  float* out = (float*)d_out;

  unsigned short* xhi = (unsigned short*)d_ws;                      // 4.46 MB
  const size_t xbytes = (size_t)kTok * kXStride * 2;
  const size_t wtbytes = (size_t)kE * kOut * kIn * 2;               // 46.1 MB

  hqq_prep<<<dim3(kTok), dim3(256), 0, stream>>>(x, xhi);

  if (ws_size >= xbytes + wtbytes) {
    // primary: dequant once, then plain grouped bf16 GEMM (m97 structure)
    unsigned short* wt = xhi + (size_t)kTok * kXStride;
    hqq_dequant<<<dim3(5632), dim3(256), 0, stream>>>(wq, scales, zeros, wt);
    hqq_gemm2<<<dim3(kGrid), dim3(256), 0, stream>>>(xhi, wt, tpe, out);
  } else {
    // fallback: round-6 kernel (in-loop dequant)
    hqq_gemm<<<dim3(kGrid), dim3(256), 0, stream>>>(xhi, wq, scales, zeros, tpe, out);
  }
}